// Round 9
// baseline (176.947 us; speedup 1.0000x reference)
//
#include <hip/hip_runtime.h>

typedef _Float16 f16;
typedef _Float16 f16x2 __attribute__((ext_vector_type(2)));
typedef _Float16 f16x4 __attribute__((ext_vector_type(4)));
typedef _Float16 f16x8 __attribute__((ext_vector_type(8)));
typedef float    f32x4 __attribute__((ext_vector_type(4)));

// Geometry:
//   x:   (4,128,64,64) f32     p5: (128,21,64,64) f32
//   p6:  (128,21,128)  f32     out:(4,128,64,64)  f32
// Workspace:
//   xk  [3][4][128][82][64] f16 = x*(1/8), pre-shifted per kc, zero-padded rows
//   t6T [4][128][2688]      f16 = p6 * t3, d-major
//   t3p [8][4][11][128][128] f16 = split-K Gram partials, rki 0..10 ONLY
//        (t3[c,rk,d] = t3[d,20-rk,c] exactly — lag symmetry; ep mirrors rk>=11)
//   t8p [4][4][64][128][64]  f16 = split-K out partials (g,n,h,d,w), ALIASES t3p
#define XROWS 82
#define XSTR  (XROWS * 64)
#define XK_ELEMS (3u * 4u * 128u * (unsigned)XSTR)
static const size_t T6T_OFF   = (size_t)XK_ELEMS * 2;                 // 16.12 MB
static const size_t T6T_BYTES = (size_t)4 * 128 * 2688 * 2;           // 2.75 MB
static const size_t T3P_OFF   = T6T_OFF + T6T_BYTES;
static const size_t T8P_OFF   = T3P_OFF;   // t3p dead before outp writes t8p

__device__ __forceinline__ void gl16(const f16* g, f16* l) {
  __builtin_amdgcn_global_load_lds((const __attribute__((address_space(1))) void*)g,
                                   (__attribute__((address_space(3))) void*)l, 16, 0, 0);
}

// ---------------------------------------------------------------- prep v2 (xk, w-inner, 16B stores)
// grid 3936 = 1,007,616 f16x8 groups / 256; one vec-8 store per thread.
__global__ __launch_bounds__(256) void prep_kernel(const float* __restrict__ x,
                                                   f16* __restrict__ xk) {
  unsigned p = blockIdx.x * 256u + threadIdx.x;      // f16x8 index (exact grid)
  unsigned rest = p / 656u;                          // 656 = 82 rows * 8 groups
  unsigned q    = p - rest * 656u;
  unsigned row  = q >> 3;
  unsigned wp   = q & 7u;
  unsigned c    = rest & 127u;
  unsigned n    = (rest >> 7) & 3u;
  unsigned kc   = rest >> 9;

  int hsrc = (int)row - 9;
  f16x8 v = {};
  if (hsrc >= 0 && hsrc < 64) {
    const float* base = x + (((size_t)(n * 128u + c) * 64u + (unsigned)hsrc) * 64u);
    int w0 = (int)(wp * 8u) + 2 * (int)kc - 2;
#pragma unroll
    for (int i = 0; i < 8; i++) {
      int wsrc = w0 + i;
      v[i] = (wsrc >= 0 && wsrc < 64) ? (f16)(base[wsrc] * 0.125f) : (f16)0.f;
    }
  }
  ((f16x8*)xk)[p] = v;
}

// ---------------------------------------------------------------- gram (LDS-staged, rki 0..10, split-K)
// grid 704 = n(4)*rki(11)*cseg(2)*ks(8); block 256 (4 waves 2x2), tile 64c x 128d, K-slice 512, 8 steps.
__global__ __launch_bounds__(256, 3) void gram_kernel(const f16* __restrict__ xk,
                                                      f16* __restrict__ t3p) {
  __shared__ f16 gl[2 * 12288];

  unsigned b    = blockIdx.x;
  unsigned ks   = b & 7u;
  unsigned cseg = (b >> 3) & 1u;
  unsigned rki  = (b >> 4) % 11u;
  unsigned n    = b / 176u;
  unsigned r    = rki / 3u;
  unsigned kc   = rki - r * 3u;

  unsigned tid  = threadIdx.x;
  unsigned wv   = tid >> 6;
  unsigned lane = tid & 63u;
  unsigned wy   = wv >> 1;
  unsigned wx   = wv & 1u;
  unsigned quad = lane >> 4;
  unsigned l16  = lane & 15u;
  unsigned rsl  = lane >> 3;
  unsigned seg  = (lane & 7u) ^ (rsl & 7u);

  unsigned h0 = ks * 8u;
  const f16* Ab = xk + (size_t)(kc * 4u + n) * 128u * XSTR + (size_t)(cseg * 64u) * XSTR
                + (h0 + 3u * r) * 64u + seg * 8u;
  const f16* Bb = xk + (size_t)(4u + n) * 128u * XSTR + (h0 + 9u) * 64u + seg * 8u;
  unsigned ar0 = wv * 16u;
  unsigned br0 = wv * 32u;

  f32x4 acc[2][4] = {};

#pragma unroll
  for (unsigned t = 0; t < 2u; t++)
    gl16(Ab + (size_t)(ar0 + t * 8u + rsl) * XSTR, &gl[(ar0 + t * 8u) * 64u]);
#pragma unroll
  for (unsigned t = 0; t < 4u; t++)
    gl16(Bb + (size_t)(br0 + t * 8u + rsl) * XSTR, &gl[4096u + (br0 + t * 8u) * 64u]);

  for (unsigned s = 0; s < 8u; s++) {
    __syncthreads();
    if (s < 7u) {
      f16* base = &gl[((s + 1u) & 1u) * 12288u];
      unsigned off = (s + 1u) * 64u;
#pragma unroll
      for (unsigned t = 0; t < 2u; t++)
        gl16(Ab + off + (size_t)(ar0 + t * 8u + rsl) * XSTR, base + (ar0 + t * 8u) * 64u);
#pragma unroll
      for (unsigned t = 0; t < 4u; t++)
        gl16(Bb + off + (size_t)(br0 + t * 8u + rsl) * XSTR, base + 4096u + (br0 + t * 8u) * 64u);
    }
    const f16* bufA = &gl[(s & 1u) * 12288u];
    const f16* bufB = bufA + 4096u;
#pragma unroll
    for (unsigned t2 = 0; t2 < 2u; t2++) {
      unsigned L = t2 * 4u + quad;
      f16x8 a[2], bb[4];
#pragma unroll
      for (int ms = 0; ms < 2; ms++) {
        unsigned rr = wy * 32u + (unsigned)ms * 16u + l16;
        a[ms] = *(const f16x8*)&bufA[rr * 64u + (L ^ (rr & 7u)) * 8u];
      }
#pragma unroll
      for (int ns = 0; ns < 4; ns++) {
        unsigned rb = wx * 64u + (unsigned)ns * 16u + l16;
        bb[ns] = *(const f16x8*)&bufB[rb * 64u + (L ^ (rb & 7u)) * 8u];
      }
#pragma unroll
      for (int ms = 0; ms < 2; ms++)
#pragma unroll
        for (int ns = 0; ns < 4; ns++)
          acc[ms][ns] = __builtin_amdgcn_mfma_f32_16x16x32_f16(a[ms], bb[ns], acc[ms][ns], 0, 0, 0);
    }
  }

  f16* tp = t3p + ((size_t)(ks * 4u + n) * 11u + rki) * 16384u;
#pragma unroll
  for (int ms = 0; ms < 2; ms++) {
#pragma unroll
    for (int ns = 0; ns < 4; ns++) {
      unsigned c0 = cseg * 64u + wy * 32u + (unsigned)ms * 16u + quad * 4u;
      unsigned d  = wx * 64u + (unsigned)ns * 16u + l16;
#pragma unroll
      for (int reg = 0; reg < 4; reg++)
        tp[(size_t)(c0 + (unsigned)reg) * 128u + d] = (f16)acc[ms][ns][reg];
    }
  }
}

// ---------------------------------------------------------------- ep: t6T = p6 * t3 (mirror for rk>=11)
__global__ __launch_bounds__(256) void ep_kernel(const f16* __restrict__ t3p,
                                                 const float* __restrict__ p6,
                                                 f16* __restrict__ t6T) {
  unsigned idx = blockIdx.x * 256u + threadIdx.x;   // < 344064
  unsigned t   = idx >> 12;                          // n*21+rk
  unsigned rk  = t % 21u;
  unsigned n   = t / 21u;

  if (rk <= 10u) {
    unsigned d4 = idx & 31u;
    unsigned c  = (idx >> 5) & 127u;
    unsigned d0 = d4 * 4u;
    float s0 = 0.f, s1 = 0.f, s2 = 0.f, s3 = 0.f;
#pragma unroll
    for (unsigned ks = 0; ks < 8u; ks++) {
      f16x4 v = *(const f16x4*)(t3p + (((size_t)(ks * 4u + n) * 11u + rk) * 16384u + c * 128u + d0));
      s0 += (float)v[0]; s1 += (float)v[1]; s2 += (float)v[2]; s3 += (float)v[3];
    }
    const float* pp = p6 + ((size_t)c * 21u + rk) * 128u + d0;
    f16* ob = t6T + (size_t)(n * 128u + d0) * 2688u + rk * 128u + c;
    ob[0]        = (f16)(s0 * pp[0]);
    ob[2688]     = (f16)(s1 * pp[1]);
    ob[2 * 2688] = (f16)(s2 * pp[2]);
    ob[3 * 2688] = (f16)(s3 * pp[3]);
  } else {
    unsigned mrk = 20u - rk;          // t3[c,rk,d] = t3p_sum[mrk][d][c]
    unsigned c4 = idx & 31u;
    unsigned d  = (idx >> 5) & 127u;
    unsigned c0 = c4 * 4u;
    float s0 = 0.f, s1 = 0.f, s2 = 0.f, s3 = 0.f;
#pragma unroll
    for (unsigned ks = 0; ks < 8u; ks++) {
      f16x4 v = *(const f16x4*)(t3p + (((size_t)(ks * 4u + n) * 11u + mrk) * 16384u + d * 128u + c0));
      s0 += (float)v[0]; s1 += (float)v[1]; s2 += (float)v[2]; s3 += (float)v[3];
    }
    f16x4 o;
    o[0] = (f16)(s0 * p6[((size_t)(c0 + 0u) * 21u + rk) * 128u + d]);
    o[1] = (f16)(s1 * p6[((size_t)(c0 + 1u) * 21u + rk) * 128u + d]);
    o[2] = (f16)(s2 * p6[((size_t)(c0 + 2u) * 21u + rk) * 128u + d]);
    o[3] = (f16)(s3 * p6[((size_t)(c0 + 3u) * 21u + rk) * 128u + d]);
    *(f16x4*)(t6T + (size_t)(n * 128u + d) * 2688u + rk * 128u + c0) = o;
  }
}

// ---------------------------------------------------------------- outp (t8 split-K x4, f16 Rt -> 18.4 KB LDS)
// grid 1024 = n(4)*h(64)*g(4); block 256 (4 waves 2x2), tile 64w x 128d.
// LDS: staging 10.2 KB aliased with f16 Rt (128 x 72, 16B-aligned rows) = 18.4 KB total
//  -> 8 blocks/CU static (was 4 with f32 Rt), VGPR stays 60.
#define ALDS_STR 40
#define RT_STR   72   // f16 stride: row byte-stride 144 (mult of 16), bank-friendly
__global__ __launch_bounds__(256, 4) void outp_kernel(const f16* __restrict__ xk,
                                                      const float* __restrict__ p5,
                                                      const f16* __restrict__ t6T,
                                                      f16* __restrict__ t8p) {
  __shared__ f16 smem[128 * RT_STR];   // 18432 B; first 10240 B = 2 staging bufs
  f16* Alds = smem;

  unsigned b = blockIdx.x;
  unsigned g = b & 3u;
  unsigned h = (b >> 2) & 63u;
  unsigned n = b >> 8;

  unsigned tid  = threadIdx.x;
  unsigned wv   = tid >> 6;
  unsigned lane = tid & 63u;
  unsigned wy   = wv >> 1;
  unsigned wx   = wv & 1u;
  unsigned quad = lane >> 4;
  unsigned l16  = lane & 15u;
  unsigned wst  = tid & 63u;
  unsigned g8   = tid >> 6;

  unsigned cbase = g * 32u + g8 * 8u;
  const float* prow0 = p5 + (size_t)cbase * (21u * 4096u) + h * 64u + wst;
  const f16* bfb = t6T + (size_t)(n * 128u + wx * 64u + l16) * 2688u + g * 32u + quad * 8u;

  f32x4 acc[2][4] = {};
  f16 xv[8]; float pv[8];
  f16x8 bfc[4];

  { // prefetch chunk 0 (rk=0 -> r=0, kc=0)
    const f16* xrow = xk + (((size_t)n * 128u + cbase) * XROWS + h) * 64u + wst;
#pragma unroll
    for (int i = 0; i < 8; i++) { xv[i] = xrow[(size_t)i * XSTR]; pv[i] = prow0[(size_t)i * (21u * 4096u)]; }
#pragma unroll
    for (int ns = 0; ns < 4; ns++) bfc[ns] = *(const f16x8*)(bfb + (size_t)ns * 16u * 2688u);
  }

  for (unsigned j = 0; j < 21u; j++) {
    f16* Ag = Alds + (j & 1u) * 2560u;
    {
      f16x8 av;
#pragma unroll
      for (int i = 0; i < 8; i++) av[i] = (f16)((float)xv[i] * (1.0f + pv[i]));
      *(f16x8*)&Ag[wst * ALDS_STR + g8 * 8u] = av;
    }
    __syncthreads();

    f16x8 bfn[4];
    if (j < 20u) {   // register prefetch of chunk j+1 (overlaps MFMA below)
      unsigned rk = j + 1u;
      unsigned rr = rk / 3u;
      unsigned kcc = rk - rr * 3u;
      const f16* xrow = xk + (((size_t)(kcc * 4u + n) * 128u + cbase) * XROWS + (h + 3u * rr)) * 64u + wst;
      const float* prow = prow0 + rk * 4096u;
#pragma unroll
      for (int i = 0; i < 8; i++) { xv[i] = xrow[(size_t)i * XSTR]; pv[i] = prow[(size_t)i * (21u * 4096u)]; }
#pragma unroll
      for (int ns = 0; ns < 4; ns++) bfn[ns] = *(const f16x8*)(bfb + (size_t)ns * 16u * 2688u + rk * 128u);
    }

    f16x8 a[2];
#pragma unroll
    for (int ms = 0; ms < 2; ms++)
      a[ms] = *(const f16x8*)&Ag[(wy * 32u + (unsigned)ms * 16u + l16) * ALDS_STR + quad * 8u];
#pragma unroll
    for (int ms = 0; ms < 2; ms++)
#pragma unroll
      for (int ns = 0; ns < 4; ns++)
        acc[ms][ns] = __builtin_amdgcn_mfma_f32_16x16x32_f16(a[ms], bfc[ns], acc[ms][ns], 0, 0, 0);
#pragma unroll
    for (int ns = 0; ns < 4; ns++) bfc[ns] = bfn[ns];
  }

  // transpose via f16 LDS tile for coalesced partial stores: t8p[g][n][h][d][w]
  __syncthreads();
  f16* Rt = smem;
#pragma unroll
  for (int ms = 0; ms < 2; ms++)
#pragma unroll
    for (int ns = 0; ns < 4; ns++) {
      unsigned w0 = wy * 32u + (unsigned)ms * 16u + quad * 4u;
      unsigned d  = wx * 64u + (unsigned)ns * 16u + l16;
      f16x4 t;
#pragma unroll
      for (int reg = 0; reg < 4; reg++) t[reg] = (f16)acc[ms][ns][reg];
      *(f16x4*)&Rt[d * RT_STR + w0] = t;
    }
  __syncthreads();
  f16* op = t8p + ((size_t)((g * 4u + n) * 64u + h)) * 8192u;
#pragma unroll
  for (unsigned it = 0; it < 4u; it++) {
    unsigned row = (tid >> 3) + it * 32u;
    unsigned w0  = (tid & 7u) * 8u;
    f16x8 o = *(const f16x8*)&Rt[row * RT_STR + w0];
    *(f16x8*)(op + row * 64u + w0) = o;
  }
}

// ---------------------------------------------------------------- red: out = FS * sum_g(t8p)
__global__ __launch_bounds__(256) void red_kernel(const f16* __restrict__ t8p,
                                                  float* __restrict__ out) {
  unsigned idx = blockIdx.x * 256u + threadIdx.x;
  unsigned w0 = (idx & 7u) * 8u;
  unsigned h  = (idx >> 3) & 63u;
  unsigned d  = (idx >> 9) & 127u;
  unsigned n  = idx >> 16;
  const float FS = 0.15430334996209192f;  // 8 / sqrt(2688)
  float s[8] = {};
#pragma unroll
  for (unsigned g = 0; g < 4u; g++) {
    f16x8 v = *(const f16x8*)(t8p + ((size_t)((g * 4u + n) * 64u + h)) * 8192u + d * 64u + w0);
#pragma unroll
    for (int i = 0; i < 8; i++) s[i] += (float)v[i];
  }
  f32x4 o0, o1;
#pragma unroll
  for (int i = 0; i < 4; i++) { o0[i] = s[i] * FS; o1[i] = s[i + 4] * FS; }
  float* op = out + ((size_t)(n * 128u + d) * 64u + h) * 64u + w0;
  *(f32x4*)op = o0;
  *(f32x4*)(op + 4) = o1;
}

// ---------------------------------------------------------------- launch
extern "C" void kernel_launch(void* const* d_in, const int* in_sizes, int n_in,
                              void* d_out, int out_size, void* d_ws, size_t ws_size,
                              hipStream_t stream) {
  const float* x  = (const float*)d_in[0];
  const float* p5 = (const float*)d_in[1];
  const float* p6 = (const float*)d_in[2];
  float* out = (float*)d_out;
  f16* xk  = (f16*)((char*)d_ws);
  f16* t6T = (f16*)((char*)d_ws + T6T_OFF);
  f16* t3p = (f16*)((char*)d_ws + T3P_OFF);
  f16* t8p = (f16*)((char*)d_ws + T8P_OFF);   // aliases t3p (dead after ep)

  hipLaunchKernelGGL(prep_kernel, dim3(3936), dim3(256), 0, stream, x, xk);
  hipLaunchKernelGGL(gram_kernel, dim3(704),  dim3(256), 0, stream, xk, t3p);
  hipLaunchKernelGGL(ep_kernel,   dim3(1344), dim3(256), 0, stream, t3p, p6, t6T);
  hipLaunchKernelGGL(outp_kernel, dim3(1024), dim3(256), 0, stream, xk, p5, t6T, t8p);
  hipLaunchKernelGGL(red_kernel,  dim3(1024), dim3(256), 0, stream, t8p, out);
}